// Round 5
// baseline (257.648 us; speedup 1.0000x reference)
//
#include <hip/hip_runtime.h>
#include <hip/hip_bf16.h>

typedef __bf16 bf16;
typedef bf16 bf16x8 __attribute__((ext_vector_type(8)));
typedef bf16 bf16x4 __attribute__((ext_vector_type(4)));
typedef float f32x4 __attribute__((ext_vector_type(4)));
typedef float f32x16 __attribute__((ext_vector_type(16)));
typedef unsigned int uint2v __attribute__((ext_vector_type(2)));

#define MFMA16(a, b, c) __builtin_amdgcn_mfma_f32_16x16x32_bf16(a, b, c, 0, 0, 0)
#define MFMA32(a, b, c) __builtin_amdgcn_mfma_f32_32x32x16_bf16(a, b, c, 0, 0, 0)

constexpr int Bn = 4, Sn = 2048, Dn = 1024, Hn = 16, HDn = 64;
constexpr int Mn = Bn * Sn;  // 8192

__device__ __forceinline__ bf16x8 cvt8(float4 a, float4 b) {
  bf16x8 v = {(bf16)a.x, (bf16)a.y, (bf16)a.z, (bf16)a.w,
              (bf16)b.x, (bf16)b.y, (bf16)b.z, (bf16)b.w};
  return v;
}

// async global->LDS, 16B per lane; LDS dest is wave-uniform base + lane*16
__device__ __forceinline__ void load_lds16(const bf16* g, bf16* l) {
  __builtin_amdgcn_global_load_lds(
      (const __attribute__((address_space(1))) void*)g,
      (__attribute__((address_space(3))) void*)l, 16, 0, 0);
}

__device__ __forceinline__ unsigned cvt_pk_bf16(float lo, float hi) {
  unsigned r;
  asm("v_cvt_pk_bf16_f32 %0, %1, %2" : "=v"(r) : "v"(lo), "v"(hi));
  return r;
}

// ------- merged preprocessing: cvt hidden + transpose both weights ----------
__global__ __launch_bounds__(256) void k_prep(const float* __restrict__ hidden,
                                              const float* __restrict__ w_attn,
                                              const float* __restrict__ w_proj,
                                              bf16* __restrict__ Xb,
                                              bf16* __restrict__ wattnT,
                                              bf16* __restrict__ wprojT) {
  __shared__ alignas(16) bf16 t[64][72];
  const int bx = blockIdx.x;
  const int tid = threadIdx.x;
  if (bx < 4096) {  // ---- cvt ----
    int i = bx * 256 + tid;
    const float4* p = (const float4*)hidden + (size_t)i * 2;
    float4 a = p[0], b = p[1];
    *((bf16x8*)Xb + i) = cvt8(a, b);
    return;
  }
  // ---- transpose+cvt ----
  const float* in;
  bf16* out;
  int K = 1024, N, n0, k0;
  if (bx < 4864) {
    int idx = bx - 4096;  // 48 x 16
    in = w_attn; out = wattnT; N = 3072;
    n0 = (idx % 48) * 64; k0 = (idx / 48) * 64;
  } else {
    int idx = bx - 4864;  // 16 x 16
    in = w_proj; out = wprojT; N = 1024;
    n0 = (idx % 16) * 64; k0 = (idx / 16) * 64;
  }
  {
    int row = tid >> 2;
    int c16 = (tid & 3) * 16;
    const float* src = in + (size_t)(k0 + row) * N + n0 + c16;
    float4 f0 = ((const float4*)src)[0];
    float4 f1 = ((const float4*)src)[1];
    float4 f2 = ((const float4*)src)[2];
    float4 f3 = ((const float4*)src)[3];
    *(bf16x8*)&t[row][c16] = cvt8(f0, f1);
    *(bf16x8*)&t[row][c16 + 8] = cvt8(f2, f3);
  }
  __syncthreads();
#pragma unroll
  for (int i = 0; i < 2; i++) {
    int c = tid + i * 256;
    int nrow = c >> 3, kcol8 = (c & 7) * 8;
    bf16x8 v;
#pragma unroll
    for (int j = 0; j < 8; j++) v[j] = t[kcol8 + j][nrow];
    *(bf16x8*)(out + (size_t)(n0 + nrow) * K + k0 + kcol8) = v;
  }
}

// ======= 128x128 GEMM cores, triple-buffered counted-vmcnt K-loop ==========
// Round-4 lesson: runtime buffer rotation (la[cb]) defeated constant folding
// -> VALUBusy 17->46%, regression. This version hard-codes buffer indices
// via 3-phase macro unrolling (runtime only in the strength-reducible tile
// pointer). No LDS swizzle: at [128][32] the bank index sees only one row
// bit, so the 8-way frag-read conflict is layout-fundamental (round-4 PMC:
// swizzle changed nothing). Phase t: vmcnt(4) [tile t landed; t+1 in
// flight] -> s_barrier -> stage tile t+2 into buffer freed at t-1 ->
// ds_read (const base + imm offset) -> 16 MFMA. vmcnt(0) only at t=31.

// ------- QKV GEMM -> Q[B,H,S,HD], K[B,H,S,HD], V^T[B,H,HD,S] (all bf16) ------
__global__ __launch_bounds__(256) void k_gemm_qkv(const bf16* __restrict__ A,
                                                  const bf16* __restrict__ BT,
                                                  const float* __restrict__ bias,
                                                  bf16* __restrict__ Qo,
                                                  bf16* __restrict__ Ko,
                                                  bf16* __restrict__ Vt) {
  __shared__ alignas(16) bf16 la[3][128 * 32];
  __shared__ alignas(16) bf16 lb[3][128 * 32];
  const int tid = threadIdx.x;
  const int w = tid >> 6, lane = tid & 63, l15 = lane & 15, quad = lane >> 4;
  const int wm = w >> 1, wn = w & 1;
  const int m0 = blockIdx.y * 128, n0 = blockIdx.x * 128;
  const int lrow = lane >> 2, lcol = (lane & 3) * 8;

  // per-thread staging base pointers (advance by immediate offsets only)
  const bf16* a0 = A + (size_t)(m0 + w * 16 + lrow) * 1024 + lcol;
  const bf16* a1 = A + (size_t)(m0 + 64 + w * 16 + lrow) * 1024 + lcol;
  const bf16* b0 = BT + (size_t)(n0 + w * 16 + lrow) * 1024 + lcol;
  const bf16* b1 = BT + (size_t)(n0 + 64 + w * 16 + lrow) * 1024 + lcol;

  f32x4 acc[4][4];
#pragma unroll
  for (int i = 0; i < 4; i++)
#pragma unroll
    for (int j = 0; j < 4; j++) acc[i][j] = f32x4{0.f, 0.f, 0.f, 0.f};

#define STAGEQ(kk_, bf_)                                   \
  {                                                        \
    load_lds16(a0 + (kk_), &la[bf_][w * 512]);             \
    load_lds16(a1 + (kk_), &la[bf_][(w + 4) * 512]);       \
    load_lds16(b0 + (kk_), &lb[bf_][w * 512]);             \
    load_lds16(b1 + (kk_), &lb[bf_][(w + 4) * 512]);       \
  }

#define PHASEQ(cb_, sb_, kk_, dostage_, last_)                                 \
  {                                                                            \
    if (last_) asm volatile("s_waitcnt vmcnt(0)" ::: "memory");                \
    else       asm volatile("s_waitcnt vmcnt(4)" ::: "memory");                \
    __builtin_amdgcn_s_barrier();                                              \
    if (dostage_) STAGEQ((kk_) + 64, sb_)                                      \
    bf16x8 af[4], bfr[4];                                                      \
    _Pragma("unroll")                                                          \
    for (int i = 0; i < 4; i++)                                                \
      af[i] = *(const bf16x8*)&la[cb_][(wm * 64 + i * 16 + l15) * 32 +         \
                                       quad * 8];                              \
    _Pragma("unroll")                                                          \
    for (int j = 0; j < 4; j++)                                                \
      bfr[j] = *(const bf16x8*)&lb[cb_][(wn * 64 + j * 16 + l15) * 32 +        \
                                        quad * 8];                             \
    _Pragma("unroll")                                                          \
    for (int i = 0; i < 4; i++)                                                \
      _Pragma("unroll")                                                        \
      for (int j = 0; j < 4; j++) acc[i][j] = MFMA16(af[i], bfr[j], acc[i][j]); \
  }

  STAGEQ(0, 0)
  STAGEQ(32, 1)
  // t = 0..29 in 10 macro-iters of 3 (buffer indices compile-time)
  for (int kk = 0; kk < 30 * 32; kk += 96) {
    PHASEQ(0, 2, kk, 1, 0)
    PHASEQ(1, 0, kk + 32, 1, 0)
    PHASEQ(2, 1, kk + 64, 1, 0)
  }
  PHASEQ(0, 2, 30 * 32, 0, 0)  // t=30
  PHASEQ(1, 0, 31 * 32, 0, 1)  // t=31
#undef PHASEQ
#undef STAGEQ

#pragma unroll
  for (int j = 0; j < 4; j++) {
    int ng = n0 + wn * 64 + j * 16 + l15;
    float bs = bias[ng];
    int which = ng >> 10;  // 0=Q 1=K 2=V (uniform per 16-col subtile)
    int nloc = ng & 1023, hh = nloc >> 6, hd = nloc & 63;
#pragma unroll
    for (int i = 0; i < 4; i++) {
      int mg0 = m0 + wm * 64 + i * 16 + quad * 4;
      int bb = mg0 >> 11, ss = mg0 & 2047;
      if (which == 2) {
        bf16x4 v;
#pragma unroll
        for (int r = 0; r < 4; r++) v[r] = (bf16)(acc[i][j][r] + bs);
        *(bf16x4*)&Vt[((size_t)(bb * Hn + hh) * HDn + hd) * Sn + ss] = v;
      } else {
        bf16* dst = which ? Ko : Qo;
#pragma unroll
        for (int r = 0; r < 4; r++)
          dst[((size_t)(bb * Hn + hh) * Sn + ss + r) * HDn + hd] =
              (bf16)(acc[i][j][r] + bs);
      }
    }
  }
}

// ------- proj GEMM: ctx bf16 @ wprojT + bias -> out f32 -------
__global__ __launch_bounds__(256) void k_gemm_proj(const bf16* __restrict__ A,
                                                   const bf16* __restrict__ BT,
                                                   const float* __restrict__ bias,
                                                   float* __restrict__ out) {
  __shared__ alignas(16) bf16 la[3][128 * 32];
  __shared__ alignas(16) bf16 lb[3][128 * 32];
  const int tid = threadIdx.x;
  const int w = tid >> 6, lane = tid & 63, l15 = lane & 15, quad = lane >> 4;
  const int wm = w >> 1, wn = w & 1;
  const int m0 = blockIdx.y * 128, n0 = blockIdx.x * 128;
  const int lrow = lane >> 2, lcol = (lane & 3) * 8;

  const bf16* a0 = A + (size_t)(m0 + w * 16 + lrow) * 1024 + lcol;
  const bf16* a1 = A + (size_t)(m0 + 64 + w * 16 + lrow) * 1024 + lcol;
  const bf16* b0 = BT + (size_t)(n0 + w * 16 + lrow) * 1024 + lcol;
  const bf16* b1 = BT + (size_t)(n0 + 64 + w * 16 + lrow) * 1024 + lcol;

  f32x4 acc[4][4];
#pragma unroll
  for (int i = 0; i < 4; i++)
#pragma unroll
    for (int j = 0; j < 4; j++) acc[i][j] = f32x4{0.f, 0.f, 0.f, 0.f};

#define STAGEP(kk_, bf_)                                   \
  {                                                        \
    load_lds16(a0 + (kk_), &la[bf_][w * 512]);             \
    load_lds16(a1 + (kk_), &la[bf_][(w + 4) * 512]);       \
    load_lds16(b0 + (kk_), &lb[bf_][w * 512]);             \
    load_lds16(b1 + (kk_), &lb[bf_][(w + 4) * 512]);       \
  }

#define PHASEP(cb_, sb_, kk_, dostage_, last_)                                 \
  {                                                                            \
    if (last_) asm volatile("s_waitcnt vmcnt(0)" ::: "memory");                \
    else       asm volatile("s_waitcnt vmcnt(4)" ::: "memory");                \
    __builtin_amdgcn_s_barrier();                                              \
    if (dostage_) STAGEP((kk_) + 64, sb_)                                      \
    bf16x8 af[4], bfr[4];                                                      \
    _Pragma("unroll")                                                          \
    for (int i = 0; i < 4; i++)                                                \
      af[i] = *(const bf16x8*)&la[cb_][(wm * 64 + i * 16 + l15) * 32 +         \
                                       quad * 8];                              \
    _Pragma("unroll")                                                          \
    for (int j = 0; j < 4; j++)                                                \
      bfr[j] = *(const bf16x8*)&lb[cb_][(wn * 64 + j * 16 + l15) * 32 +        \
                                        quad * 8];                             \
    _Pragma("unroll")                                                          \
    for (int i = 0; i < 4; i++)                                                \
      _Pragma("unroll")                                                        \
      for (int j = 0; j < 4; j++) acc[i][j] = MFMA16(af[i], bfr[j], acc[i][j]); \
  }

  STAGEP(0, 0)
  STAGEP(32, 1)
  for (int kk = 0; kk < 30 * 32; kk += 96) {
    PHASEP(0, 2, kk, 1, 0)
    PHASEP(1, 0, kk + 32, 1, 0)
    PHASEP(2, 1, kk + 64, 1, 0)
  }
  PHASEP(0, 2, 30 * 32, 0, 0)  // t=30
  PHASEP(1, 0, 31 * 32, 0, 1)  // t=31
#undef PHASEP
#undef STAGEP

#pragma unroll
  for (int j = 0; j < 4; j++) {
    int ng = n0 + wn * 64 + j * 16 + l15;
    float bs = bias[ng];
#pragma unroll
    for (int i = 0; i < 4; i++) {
      int mg0 = m0 + wm * 64 + i * 16 + quad * 4;
#pragma unroll
      for (int r = 0; r < 4; r++)
        out[(size_t)(mg0 + r) * 1024 + ng] = acc[i][j][r] + bs;
    }
  }
}

// ------- flash attention, 32x32 swapped-QK^T, in-register softmax ----------
// Triple-buffered K/V staging with counted vmcnt (validated round 3).
__global__ __launch_bounds__(256) void k_attn(const bf16* __restrict__ Q,
                                              const bf16* __restrict__ Kv,
                                              const bf16* __restrict__ Vtg,
                                              bf16* __restrict__ ctx) {
  __shared__ alignas(16) bf16 kl[3][64 * 64];
  __shared__ alignas(16) bf16 vl[3][64 * 64];

  const int bh = blockIdx.x;
  const int qt = 15 - blockIdx.y;  // longest blocks launch first
  const int bb = bh >> 4, hh = bh & 15;
  const int tid = threadIdx.x;
  const int w = tid >> 6, lane = tid & 63, l31 = lane & 31, hi = lane >> 5;
  const size_t base = (size_t)bh * Sn * HDn;
  const int q0 = qt * 128 + w * 32;
  const int nt = 2 * qt + 2;  // 64-key tiles this block consumes

  const int r0 = tid >> 3, s0 = tid & 7;
  const int ksw = (s0 ^ (r0 & 7)) << 3;
  const bf16* Krow = Kv + base + (size_t)r0 * 64 + ksw;
  const bf16* Vrow0 = Vtg + ((size_t)bh * 64 + r0) * Sn + ksw;
  const bf16* Vrow1 = Vtg + ((size_t)bh * 64 + r0 + 32) * Sn + ksw;
  const int sw7 = l31 & 7;

  bf16x8 qf[4];
#pragma unroll
  for (int c = 0; c < 4; c++) {
    bf16x8 v = *(const bf16x8*)(Q + base + (size_t)(q0 + l31) * 64 + c * 16 + hi * 8);
#pragma unroll
    for (int e = 0; e < 8; e++) v[e] = (bf16)((float)v[e] * 0.125f);
    qf[c] = v;
  }

  f32x16 o0, o1;
#pragma unroll
  for (int e = 0; e < 16; e++) { o0[e] = 0.f; o1[e] = 0.f; }
  float dsum = 0.f;

#define STAGE(t_, bf_)                                                  \
  {                                                                     \
    const int kb_ = (t_) * 64;                                          \
    load_lds16(Krow + (size_t)kb_ * 64, &kl[bf_][w * 512]);             \
    load_lds16(Krow + (size_t)(kb_ + 32) * 64, &kl[bf_][2048 + w * 512]); \
    load_lds16(Vrow0 + kb_, &vl[bf_][w * 512]);                         \
    load_lds16(Vrow1 + kb_, &vl[bf_][2048 + w * 512]);                  \
  }

  STAGE(0, 0)
  STAGE(1, 1)  // nt >= 2 always

  int cb = 0, sb = 2;  // compute buffer (t%3), stage buffer ((t+2)%3)
  for (int t = 0; t < nt; ++t) {
    if (t == nt - 1) asm volatile("s_waitcnt vmcnt(0)" ::: "memory");
    else             asm volatile("s_waitcnt vmcnt(4)" ::: "memory");
    __builtin_amdgcn_s_barrier();  // now ALL waves' tile-t rows are in LDS
    if (t + 2 < nt) STAGE(t + 2, sb)
    const int kb = t * 64;
    if (kb <= q0 + 31) {
      const bf16* klc = kl[cb];
      const bf16* vlc = vl[cb];
#pragma unroll
      for (int sub = 0; sub < 2; sub++) {
        const int ks0 = kb + sub * 32;
        if (ks0 > q0 + 31) break;
        f32x16 st;
#pragma unroll
        for (int e = 0; e < 16; e++) st[e] = 0.f;
#pragma unroll
        for (int c = 0; c < 4; c++) {
          const int row = sub * 32 + l31;
          bf16x8 kf = *(const bf16x8*)&klc[row * 64 + (((2 * c + hi) ^ sw7) << 3)];
          st = MFMA32(kf, qf[c], st);
        }
        if (ks0 == q0) {
#pragma unroll
          for (int r = 0; r < 16; r++) {
            int krel = (r & 3) + 8 * (r >> 2) + 4 * hi;
            if (krel > l31) st[r] = -1e30f;
          }
        }
#pragma unroll
        for (int r = 0; r < 16; r++) {
          st[r] = __expf(st[r]);
          dsum += st[r];
        }
#pragma unroll
        for (int c2 = 0; c2 < 2; c2++) {
          unsigned wa0 = cvt_pk_bf16(st[8 * c2 + 0], st[8 * c2 + 1]);
          unsigned wa1 = cvt_pk_bf16(st[8 * c2 + 2], st[8 * c2 + 3]);
          unsigned wb0 = cvt_pk_bf16(st[8 * c2 + 4], st[8 * c2 + 5]);
          unsigned wb1 = cvt_pk_bf16(st[8 * c2 + 6], st[8 * c2 + 7]);
          unsigned pw0, pw1, pw2, pw3;
#if __has_builtin(__builtin_amdgcn_permlane32_swap)
          uint2v sw0 = __builtin_amdgcn_permlane32_swap(wa0, wb0, false, false);
          uint2v sw1 = __builtin_amdgcn_permlane32_swap(wa1, wb1, false, false);
          pw0 = sw0.x; pw1 = sw1.x; pw2 = sw0.y; pw3 = sw1.y;
#else
          unsigned xa0 = __shfl_xor((int)wa0, 32, 64), xb0 = __shfl_xor((int)wb0, 32, 64);
          unsigned xa1 = __shfl_xor((int)wa1, 32, 64), xb1 = __shfl_xor((int)wb1, 32, 64);
          pw0 = hi ? xb0 : wa0; pw1 = hi ? xb1 : wa1;
          pw2 = hi ? wb0 : xa0; pw3 = hi ? wb1 : xa1;
#endif
          union { unsigned u[4]; bf16x8 v; } pb;
          pb.u[0] = pw0; pb.u[1] = pw1; pb.u[2] = pw2; pb.u[3] = pw3;
          const int vs = sub * 4 + 2 * c2;
          bf16x8 vf0 = *(const bf16x8*)&vlc[l31 * 64 + (((vs + hi) ^ sw7) << 3)];
          o0 = MFMA32(vf0, pb.v, o0);
          bf16x8 vf1 = *(const bf16x8*)&vlc[(32 + l31) * 64 + (((vs + hi) ^ sw7) << 3)];
          o1 = MFMA32(vf1, pb.v, o1);
        }
      }
    }
    cb = (cb == 2) ? 0 : cb + 1;
    sb = (sb == 2) ? 0 : sb + 1;
  }
#undef STAGE

  float tot = dsum + __shfl_xor(dsum, 32, 64);
  float inv = 1.f / fmaxf(tot, 1e-20f);
  size_t ob = ((size_t)(bb * Sn + q0 + l31)) * Dn + hh * HDn + hi * 4;
#pragma unroll
  for (int g = 0; g < 4; g++) {
    bf16x4 v0, v1;
#pragma unroll
    for (int r = 0; r < 4; r++) {
      v0[r] = (bf16)(o0[4 * g + r] * inv);
      v1[r] = (bf16)(o1[4 * g + r] * inv);
    }
    *(bf16x4*)&ctx[ob + g * 8] = v0;
    *(bf16x4*)&ctx[ob + 32 + g * 8] = v1;
  }
}

extern "C" void kernel_launch(void* const* d_in, const int* in_sizes, int n_in,
                              void* d_out, int out_size, void* d_ws, size_t ws_size,
                              hipStream_t stream) {
  const float* hidden = (const float*)d_in[0];   // [8192,1024] f32
  const float* w_attn = (const float*)d_in[1];   // [1024,3072] f32
  const float* b_attn = (const float*)d_in[2];   // [3072] f32
  const float* w_proj = (const float*)d_in[3];   // [1024,1024] f32
  const float* b_proj = (const float*)d_in[4];   // [1024] f32
  float* out = (float*)d_out;                    // [8192,1024] f32

  bf16* ws = (bf16*)d_ws;
  const size_t QKV_ELEMS = (size_t)Bn * Hn * Sn * HDn;  // 8388608
  bf16* Qb = ws;
  bf16* Kb = Qb + QKV_ELEMS;
  bf16* Vt = Kb + QKV_ELEMS;
  bf16* ctx = Vt + QKV_ELEMS;     // doubles as Xb (dead before k_attn writes ctx)
  bf16* Xb = ctx;
  bf16* wattnT = ctx + (size_t)Mn * Dn;
  bf16* wprojT = wattnT + (size_t)Dn * 3 * Dn;

  k_prep<<<5120, 256, 0, stream>>>(hidden, w_attn, w_proj, Xb, wattnT, wprojT);
  k_gemm_qkv<<<dim3(24, 64), 256, 0, stream>>>(Xb, wattnT, b_attn, Qb, Kb, Vt);
  k_attn<<<dim3(64, 16), 256, 0, stream>>>(Qb, Kb, Vt, ctx);
  k_gemm_proj<<<dim3(8, 64), 256, 0, stream>>>(ctx, wprojT, b_proj, out);
}

// Round 6
// 240.733 us; speedup vs baseline: 1.0703x; 1.0703x over previous
//
#include <hip/hip_runtime.h>
#include <hip/hip_bf16.h>

typedef __bf16 bf16;
typedef bf16 bf16x8 __attribute__((ext_vector_type(8)));
typedef bf16 bf16x4 __attribute__((ext_vector_type(4)));
typedef float f32x4 __attribute__((ext_vector_type(4)));
typedef float f32x16 __attribute__((ext_vector_type(16)));
typedef unsigned int uint2v __attribute__((ext_vector_type(2)));

#define MFMA16(a, b, c) __builtin_amdgcn_mfma_f32_16x16x32_bf16(a, b, c, 0, 0, 0)
#define MFMA32(a, b, c) __builtin_amdgcn_mfma_f32_32x32x16_bf16(a, b, c, 0, 0, 0)

constexpr int Bn = 4, Sn = 2048, Dn = 1024, Hn = 16, HDn = 64;
constexpr int Mn = Bn * Sn;  // 8192

__device__ __forceinline__ bf16x8 cvt8(float4 a, float4 b) {
  bf16x8 v = {(bf16)a.x, (bf16)a.y, (bf16)a.z, (bf16)a.w,
              (bf16)b.x, (bf16)b.y, (bf16)b.z, (bf16)b.w};
  return v;
}

// async global->LDS, 16B per lane; LDS dest is wave-uniform base + lane*16
__device__ __forceinline__ void load_lds16(const bf16* g, bf16* l) {
  __builtin_amdgcn_global_load_lds(
      (const __attribute__((address_space(1))) void*)g,
      (__attribute__((address_space(3))) void*)l, 16, 0, 0);
}

__device__ __forceinline__ unsigned cvt_pk_bf16(float lo, float hi) {
  unsigned r;
  asm("v_cvt_pk_bf16_f32 %0, %1, %2" : "=v"(r) : "v"(lo), "v"(hi));
  return r;
}

// ------- merged preprocessing: cvt hidden + transpose both weights ----------
__global__ __launch_bounds__(256) void k_prep(const float* __restrict__ hidden,
                                              const float* __restrict__ w_attn,
                                              const float* __restrict__ w_proj,
                                              bf16* __restrict__ Xb,
                                              bf16* __restrict__ wattnT,
                                              bf16* __restrict__ wprojT) {
  __shared__ alignas(16) bf16 t[64][72];
  const int bx = blockIdx.x;
  const int tid = threadIdx.x;
  if (bx < 4096) {  // ---- cvt ----
    int i = bx * 256 + tid;
    const float4* p = (const float4*)hidden + (size_t)i * 2;
    float4 a = p[0], b = p[1];
    *((bf16x8*)Xb + i) = cvt8(a, b);
    return;
  }
  // ---- transpose+cvt ----
  const float* in;
  bf16* out;
  int K = 1024, N, n0, k0;
  if (bx < 4864) {
    int idx = bx - 4096;  // 48 x 16
    in = w_attn; out = wattnT; N = 3072;
    n0 = (idx % 48) * 64; k0 = (idx / 48) * 64;
  } else {
    int idx = bx - 4864;  // 16 x 16
    in = w_proj; out = wprojT; N = 1024;
    n0 = (idx % 16) * 64; k0 = (idx / 16) * 64;
  }
  {
    int row = tid >> 2;
    int c16 = (tid & 3) * 16;
    const float* src = in + (size_t)(k0 + row) * N + n0 + c16;
    float4 f0 = ((const float4*)src)[0];
    float4 f1 = ((const float4*)src)[1];
    float4 f2 = ((const float4*)src)[2];
    float4 f3 = ((const float4*)src)[3];
    *(bf16x8*)&t[row][c16] = cvt8(f0, f1);
    *(bf16x8*)&t[row][c16 + 8] = cvt8(f2, f3);
  }
  __syncthreads();
#pragma unroll
  for (int i = 0; i < 2; i++) {
    int c = tid + i * 256;
    int nrow = c >> 3, kcol8 = (c & 7) * 8;
    bf16x8 v;
#pragma unroll
    for (int j = 0; j < 8; j++) v[j] = t[kcol8 + j][nrow];
    *(bf16x8*)(out + (size_t)(n0 + nrow) * K + k0 + kcol8) = v;
  }
}

// ======= m97-style 128x128 GEMM core (proven round-3 form) =================
// Round 4/5 lessons: counted-vmcnt pipelines regress at this shape (the T4
// technique needs the full 8-phase 256^2 structure, which grid quantization
// spoils here: 384 blocks x 1 block/CU). Keep the 2-barrier loop; instead
// fix L2 locality with a bijective XCD-banded block swizzle (T1): blocks
// dispatch round-robin over 8 XCDs by linear bid, so taking xcd=bid&7 and
// giving each xcd a contiguous 8-row band of m-panels makes the per-XCD
// working set (A-band 2MB + B panels) L2-resident, instead of every XCD
// streaming all 16.8MB of A.

// ------- QKV GEMM -> Q[B,H,S,HD], K[B,H,S,HD], V^T[B,H,HD,S] (all bf16) ------
__global__ __launch_bounds__(256) void k_gemm_qkv(const bf16* __restrict__ A,
                                                  const bf16* __restrict__ BT,
                                                  const float* __restrict__ bias,
                                                  bf16* __restrict__ Qo,
                                                  bf16* __restrict__ Ko,
                                                  bf16* __restrict__ Vt) {
  __shared__ alignas(16) bf16 la[128 * 32];
  __shared__ alignas(16) bf16 lb[128 * 32];
  const int tid = threadIdx.x;
  const int w = tid >> 6, lane = tid & 63, l15 = lane & 15, quad = lane >> 4;
  const int wm = w >> 1, wn = w & 1;
  // XCD-banded swizzle: 1536 blocks = 8 xcd x (8 m-band x 24 n)
  const int bid = blockIdx.x;
  const int xcd = bid & 7, idx = bid >> 3;
  const int by = xcd * 8 + idx / 24;   // 0..63  (each xcd: contiguous m-band)
  const int bx = idx % 24;             // 0..23
  const int m0 = by * 128, n0 = bx * 128;
  const int lrow = lane >> 2, lcol = (lane & 3) * 8;

  f32x4 acc[4][4];
#pragma unroll
  for (int i = 0; i < 4; i++)
#pragma unroll
    for (int j = 0; j < 4; j++) acc[i][j] = f32x4{0.f, 0.f, 0.f, 0.f};

  for (int k0 = 0; k0 < 1024; k0 += 32) {
    __syncthreads();
    load_lds16(A + (size_t)(m0 + w * 16 + lrow) * 1024 + k0 + lcol, &la[w * 512]);
    load_lds16(A + (size_t)(m0 + 64 + w * 16 + lrow) * 1024 + k0 + lcol, &la[(w + 4) * 512]);
    load_lds16(BT + (size_t)(n0 + w * 16 + lrow) * 1024 + k0 + lcol, &lb[w * 512]);
    load_lds16(BT + (size_t)(n0 + 64 + w * 16 + lrow) * 1024 + k0 + lcol, &lb[(w + 4) * 512]);
    __syncthreads();
    bf16x8 af[4], bfr[4];
#pragma unroll
    for (int i = 0; i < 4; i++)
      af[i] = *(const bf16x8*)&la[(wm * 64 + i * 16 + l15) * 32 + quad * 8];
#pragma unroll
    for (int j = 0; j < 4; j++)
      bfr[j] = *(const bf16x8*)&lb[(wn * 64 + j * 16 + l15) * 32 + quad * 8];
#pragma unroll
    for (int i = 0; i < 4; i++)
#pragma unroll
      for (int j = 0; j < 4; j++) acc[i][j] = MFMA16(af[i], bfr[j], acc[i][j]);
  }

#pragma unroll
  for (int j = 0; j < 4; j++) {
    int ng = n0 + wn * 64 + j * 16 + l15;
    float bs = bias[ng];
    int which = ng >> 10;  // 0=Q 1=K 2=V (uniform per 16-col subtile)
    int nloc = ng & 1023, hh = nloc >> 6, hd = nloc & 63;
#pragma unroll
    for (int i = 0; i < 4; i++) {
      int mg0 = m0 + wm * 64 + i * 16 + quad * 4;
      int bb = mg0 >> 11, ss = mg0 & 2047;
      if (which == 2) {
        bf16x4 v;
#pragma unroll
        for (int r = 0; r < 4; r++) v[r] = (bf16)(acc[i][j][r] + bs);
        *(bf16x4*)&Vt[((size_t)(bb * Hn + hh) * HDn + hd) * Sn + ss] = v;
      } else {
        bf16* dst = which ? Ko : Qo;
#pragma unroll
        for (int r = 0; r < 4; r++)
          dst[((size_t)(bb * Hn + hh) * Sn + ss + r) * HDn + hd] =
              (bf16)(acc[i][j][r] + bs);
      }
    }
  }
}

// ------- proj GEMM: ctx bf16 @ wprojT + bias -> out f32 -------
__global__ __launch_bounds__(256) void k_gemm_proj(const bf16* __restrict__ A,
                                                   const bf16* __restrict__ BT,
                                                   const float* __restrict__ bias,
                                                   float* __restrict__ out) {
  __shared__ alignas(16) bf16 la[128 * 32];
  __shared__ alignas(16) bf16 lb[128 * 32];
  const int tid = threadIdx.x;
  const int w = tid >> 6, lane = tid & 63, l15 = lane & 15, quad = lane >> 4;
  const int wm = w >> 1, wn = w & 1;
  // XCD-banded swizzle: 512 blocks = 8 xcd x (8 m-band x 8 n)
  const int bid = blockIdx.x;
  const int xcd = bid & 7, idx = bid >> 3;
  const int by = xcd * 8 + (idx >> 3);  // 0..63
  const int bx = idx & 7;               // 0..7
  const int m0 = by * 128, n0 = bx * 128;
  const int lrow = lane >> 2, lcol = (lane & 3) * 8;

  f32x4 acc[4][4];
#pragma unroll
  for (int i = 0; i < 4; i++)
#pragma unroll
    for (int j = 0; j < 4; j++) acc[i][j] = f32x4{0.f, 0.f, 0.f, 0.f};

  for (int k0 = 0; k0 < 1024; k0 += 32) {
    __syncthreads();
    load_lds16(A + (size_t)(m0 + w * 16 + lrow) * 1024 + k0 + lcol, &la[w * 512]);
    load_lds16(A + (size_t)(m0 + 64 + w * 16 + lrow) * 1024 + k0 + lcol, &la[(w + 4) * 512]);
    load_lds16(BT + (size_t)(n0 + w * 16 + lrow) * 1024 + k0 + lcol, &lb[w * 512]);
    load_lds16(BT + (size_t)(n0 + 64 + w * 16 + lrow) * 1024 + k0 + lcol, &lb[(w + 4) * 512]);
    __syncthreads();
    bf16x8 af[4], bfr[4];
#pragma unroll
    for (int i = 0; i < 4; i++)
      af[i] = *(const bf16x8*)&la[(wm * 64 + i * 16 + l15) * 32 + quad * 8];
#pragma unroll
    for (int j = 0; j < 4; j++)
      bfr[j] = *(const bf16x8*)&lb[(wn * 64 + j * 16 + l15) * 32 + quad * 8];
#pragma unroll
    for (int i = 0; i < 4; i++)
#pragma unroll
      for (int j = 0; j < 4; j++) acc[i][j] = MFMA16(af[i], bfr[j], acc[i][j]);
  }

#pragma unroll
  for (int j = 0; j < 4; j++) {
    int ng = n0 + wn * 64 + j * 16 + l15;
    float bs = bias[ng];
#pragma unroll
    for (int i = 0; i < 4; i++) {
      int mg0 = m0 + wm * 64 + i * 16 + quad * 4;
#pragma unroll
      for (int r = 0; r < 4; r++)
        out[(size_t)(mg0 + r) * 1024 + ng] = acc[i][j][r] + bs;
    }
  }
}

// ------- flash attention, 32x32 swapped-QK^T, in-register softmax ----------
// Triple-buffered K/V staging with counted vmcnt (validated round 3).
__global__ __launch_bounds__(256) void k_attn(const bf16* __restrict__ Q,
                                              const bf16* __restrict__ Kv,
                                              const bf16* __restrict__ Vtg,
                                              bf16* __restrict__ ctx) {
  __shared__ alignas(16) bf16 kl[3][64 * 64];
  __shared__ alignas(16) bf16 vl[3][64 * 64];

  const int bh = blockIdx.x;
  const int qt = 15 - blockIdx.y;  // longest blocks launch first
  const int bb = bh >> 4, hh = bh & 15;
  const int tid = threadIdx.x;
  const int w = tid >> 6, lane = tid & 63, l31 = lane & 31, hi = lane >> 5;
  const size_t base = (size_t)bh * Sn * HDn;
  const int q0 = qt * 128 + w * 32;
  const int nt = 2 * qt + 2;  // 64-key tiles this block consumes

  const int r0 = tid >> 3, s0 = tid & 7;
  const int ksw = (s0 ^ (r0 & 7)) << 3;
  const bf16* Krow = Kv + base + (size_t)r0 * 64 + ksw;
  const bf16* Vrow0 = Vtg + ((size_t)bh * 64 + r0) * Sn + ksw;
  const bf16* Vrow1 = Vtg + ((size_t)bh * 64 + r0 + 32) * Sn + ksw;
  const int sw7 = l31 & 7;

  bf16x8 qf[4];
#pragma unroll
  for (int c = 0; c < 4; c++) {
    bf16x8 v = *(const bf16x8*)(Q + base + (size_t)(q0 + l31) * 64 + c * 16 + hi * 8);
#pragma unroll
    for (int e = 0; e < 8; e++) v[e] = (bf16)((float)v[e] * 0.125f);
    qf[c] = v;
  }

  f32x16 o0, o1;
#pragma unroll
  for (int e = 0; e < 16; e++) { o0[e] = 0.f; o1[e] = 0.f; }
  float dsum = 0.f;

#define STAGE(t_, bf_)                                                  \
  {                                                                     \
    const int kb_ = (t_) * 64;                                          \
    load_lds16(Krow + (size_t)kb_ * 64, &kl[bf_][w * 512]);             \
    load_lds16(Krow + (size_t)(kb_ + 32) * 64, &kl[bf_][2048 + w * 512]); \
    load_lds16(Vrow0 + kb_, &vl[bf_][w * 512]);                         \
    load_lds16(Vrow1 + kb_, &vl[bf_][2048 + w * 512]);                  \
  }

  STAGE(0, 0)
  STAGE(1, 1)  // nt >= 2 always

  int cb = 0, sb = 2;  // compute buffer (t%3), stage buffer ((t+2)%3)
  for (int t = 0; t < nt; ++t) {
    if (t == nt - 1) asm volatile("s_waitcnt vmcnt(0)" ::: "memory");
    else             asm volatile("s_waitcnt vmcnt(4)" ::: "memory");
    __builtin_amdgcn_s_barrier();  // now ALL waves' tile-t rows are in LDS
    if (t + 2 < nt) STAGE(t + 2, sb)
    const int kb = t * 64;
    if (kb <= q0 + 31) {
      const bf16* klc = kl[cb];
      const bf16* vlc = vl[cb];
#pragma unroll
      for (int sub = 0; sub < 2; sub++) {
        const int ks0 = kb + sub * 32;
        if (ks0 > q0 + 31) break;
        f32x16 st;
#pragma unroll
        for (int e = 0; e < 16; e++) st[e] = 0.f;
#pragma unroll
        for (int c = 0; c < 4; c++) {
          const int row = sub * 32 + l31;
          bf16x8 kf = *(const bf16x8*)&klc[row * 64 + (((2 * c + hi) ^ sw7) << 3)];
          st = MFMA32(kf, qf[c], st);
        }
        if (ks0 == q0) {
#pragma unroll
          for (int r = 0; r < 16; r++) {
            int krel = (r & 3) + 8 * (r >> 2) + 4 * hi;
            if (krel > l31) st[r] = -1e30f;
          }
        }
#pragma unroll
        for (int r = 0; r < 16; r++) {
          st[r] = __expf(st[r]);
          dsum += st[r];
        }
#pragma unroll
        for (int c2 = 0; c2 < 2; c2++) {
          unsigned wa0 = cvt_pk_bf16(st[8 * c2 + 0], st[8 * c2 + 1]);
          unsigned wa1 = cvt_pk_bf16(st[8 * c2 + 2], st[8 * c2 + 3]);
          unsigned wb0 = cvt_pk_bf16(st[8 * c2 + 4], st[8 * c2 + 5]);
          unsigned wb1 = cvt_pk_bf16(st[8 * c2 + 6], st[8 * c2 + 7]);
          unsigned pw0, pw1, pw2, pw3;
#if __has_builtin(__builtin_amdgcn_permlane32_swap)
          uint2v sw0 = __builtin_amdgcn_permlane32_swap(wa0, wb0, false, false);
          uint2v sw1 = __builtin_amdgcn_permlane32_swap(wa1, wb1, false, false);
          pw0 = sw0.x; pw1 = sw1.x; pw2 = sw0.y; pw3 = sw1.y;
#else
          unsigned xa0 = __shfl_xor((int)wa0, 32, 64), xb0 = __shfl_xor((int)wb0, 32, 64);
          unsigned xa1 = __shfl_xor((int)wa1, 32, 64), xb1 = __shfl_xor((int)wb1, 32, 64);
          pw0 = hi ? xb0 : wa0; pw1 = hi ? xb1 : wa1;
          pw2 = hi ? wb0 : xa0; pw3 = hi ? wb1 : xa1;
#endif
          union { unsigned u[4]; bf16x8 v; } pb;
          pb.u[0] = pw0; pb.u[1] = pw1; pb.u[2] = pw2; pb.u[3] = pw3;
          const int vs = sub * 4 + 2 * c2;
          bf16x8 vf0 = *(const bf16x8*)&vlc[l31 * 64 + (((vs + hi) ^ sw7) << 3)];
          o0 = MFMA32(vf0, pb.v, o0);
          bf16x8 vf1 = *(const bf16x8*)&vlc[(32 + l31) * 64 + (((vs + hi) ^ sw7) << 3)];
          o1 = MFMA32(vf1, pb.v, o1);
        }
      }
    }
    cb = (cb == 2) ? 0 : cb + 1;
    sb = (sb == 2) ? 0 : sb + 1;
  }
#undef STAGE

  float tot = dsum + __shfl_xor(dsum, 32, 64);
  float inv = 1.f / fmaxf(tot, 1e-20f);
  size_t ob = ((size_t)(bb * Sn + q0 + l31)) * Dn + hh * HDn + hi * 4;
#pragma unroll
  for (int g = 0; g < 4; g++) {
    bf16x4 v0, v1;
#pragma unroll
    for (int r = 0; r < 4; r++) {
      v0[r] = (bf16)(o0[4 * g + r] * inv);
      v1[r] = (bf16)(o1[4 * g + r] * inv);
    }
    *(bf16x4*)&ctx[ob + g * 8] = v0;
    *(bf16x4*)&ctx[ob + 32 + g * 8] = v1;
  }
}

extern "C" void kernel_launch(void* const* d_in, const int* in_sizes, int n_in,
                              void* d_out, int out_size, void* d_ws, size_t ws_size,
                              hipStream_t stream) {
  const float* hidden = (const float*)d_in[0];   // [8192,1024] f32
  const float* w_attn = (const float*)d_in[1];   // [1024,3072] f32
  const float* b_attn = (const float*)d_in[2];   // [3072] f32
  const float* w_proj = (const float*)d_in[3];   // [1024,1024] f32
  const float* b_proj = (const float*)d_in[4];   // [1024] f32
  float* out = (float*)d_out;                    // [8192,1024] f32

  bf16* ws = (bf16*)d_ws;
  const size_t QKV_ELEMS = (size_t)Bn * Hn * Sn * HDn;  // 8388608
  bf16* Qb = ws;
  bf16* Kb = Qb + QKV_ELEMS;
  bf16* Vt = Kb + QKV_ELEMS;
  bf16* ctx = Vt + QKV_ELEMS;     // doubles as Xb (dead before k_attn writes ctx)
  bf16* Xb = ctx;
  bf16* wattnT = ctx + (size_t)Mn * Dn;
  bf16* wprojT = wattnT + (size_t)Dn * 3 * Dn;

  k_prep<<<5120, 256, 0, stream>>>(hidden, w_attn, w_proj, Xb, wattnT, wprojT);
  k_gemm_qkv<<<dim3(1536), 256, 0, stream>>>(Xb, wattnT, b_attn, Qb, Kb, Vt);
  k_attn<<<dim3(64, 16), 256, 0, stream>>>(Qb, Kb, Vt, ctx);
  k_gemm_proj<<<dim3(512), 256, 0, stream>>>(ctx, wprojT, b_proj, out);
}